// Round 1
// baseline (3422.980 us; speedup 1.0000x reference)
//
#include <hip/hip_runtime.h>

#define NB 16
#define NC 256
#define HW 2304
#define CHW 589824  // NC*HW

// ---------------- Kernel A1: per-batch partial sum of squares (fp64) ----------------
__global__ __launch_bounds__(256) void sumsq_kernel(const float* __restrict__ x,
                                                    double* __restrict__ partials) {
  const int j = blockIdx.x;   // 32 slices per batch
  const int b = blockIdx.y;   // 16 batches
  const float* xb = x + (size_t)b * CHW;
  const int base = j * (CHW / 32);  // 18432 elements per slice
  double acc = 0.0;
  for (int i = threadIdx.x; i < CHW / 32; i += 256) {
    float v = xb[base + i];
    acc += (double)v * (double)v;
  }
  __shared__ double red[256];
  red[threadIdx.x] = acc;
  __syncthreads();
  for (int s = 128; s > 0; s >>= 1) {
    if (threadIdx.x < s) red[threadIdx.x] += red[threadIdx.x + s];
    __syncthreads();
  }
  if (threadIdx.x == 0) partials[b * 32 + j] = red[0];
}

// ---------------- Kernel A2: finish reduction, write 1/xn^2 ----------------
__global__ __launch_bounds__(64) void finish_kernel(const double* __restrict__ partials,
                                                    float* __restrict__ inv_xn2) {
  const int b = blockIdx.x;
  const int t = threadIdx.x;
  double v = (t < 32) ? partials[b * 32 + t] : 0.0;
  #pragma unroll
  for (int off = 32; off > 0; off >>= 1) v += __shfl_down(v, off, 64);
  if (t == 0) inv_xn2[b] = (float)(1.0 / v);
}

// ---------------- Kernel B: 1x1 conv  tr[b][o][p] = sum_k W[o][k]*x[b][k][p] + bias[o] ----------------
__global__ __launch_bounds__(256) void conv_kernel(const float* __restrict__ x,
                                                   const float* __restrict__ W,
                                                   const float* __restrict__ bias,
                                                   float* __restrict__ trbuf) {
  const int mt = blockIdx.x;        // 0..8  -> m tile of 256
  const int c0 = blockIdx.y * 16;   // 0..15 -> 16 output channels
  const int b  = blockIdx.z;
  const int m  = mt * 256 + threadIdx.x;
  const float* xb = x + (size_t)b * CHW;
  float acc[16];
  #pragma unroll
  for (int i = 0; i < 16; ++i) acc[i] = bias[c0 + i];
  #pragma unroll 4
  for (int k = 0; k < 256; ++k) {
    const float xv = xb[(size_t)k * HW + m];
    #pragma unroll
    for (int i = 0; i < 16; ++i)
      acc[i] = fmaf(W[(size_t)(c0 + i) * 256 + k], xv, acc[i]);  // W addr wave-uniform -> s_load
  }
  float* tb = trbuf + (size_t)b * CHW;
  #pragma unroll
  for (int i = 0; i < 16; ++i) tb[(size_t)(c0 + i) * HW + m] = acc[i];
}

// ---------------- Kernel C: fused  y = relu(X1·X2/xn^2)^2 · TR ----------------
// Block: one batch b, one 32-row n-tile. Loop m in chunks of 64 (flash-style, no cos materialization).
__global__ __launch_bounds__(256, 2) void fused_kernel(const float* __restrict__ x,
                                                       const float* __restrict__ trbuf,
                                                       const float* __restrict__ inv_xn2,
                                                       float* __restrict__ out) {
  const int nt = blockIdx.x;  // 0..71
  const int b  = blockIdx.y;  // 0..15
  const int n0 = nt * 32;
  const float* xb = x + (size_t)b * CHW;
  const float* tb = trbuf + (size_t)b * CHW;
  float* ob = out + (size_t)b * CHW;
  const float inv2 = inv_xn2[b];

  __shared__ float As[256][36];  // As[k][n]: X1 tile transposed; pad 32->36 (16B-aligned rows)
  __shared__ float Bs[64][68];   // Bs[kk][m]: X2 k-slice; pad 64->68
  __shared__ float Ss[32][68];   // Ss[n][m]: relu^2 scores
  // total LDS = 36864 + 17408 + 8704 = 62976 B  (< 64 KB/block, 2 blocks/CU in 160 KB pool)

  const int tid = threadIdx.x;
  const int ti = tid >> 4;  // 0..15 -> rows 2*ti, 2*ti+1
  const int tj = tid & 15;  // 0..15 -> S cols 4*tj.., Y cols 16*tj..

  // Load X1 tile (rows are contiguous 256-float runs of the flat vector), store transposed.
  for (int i = tid; i < 32 * 256; i += 256) {
    const int n = i >> 8, k = i & 255;
    As[k][n] = xb[(size_t)(n0 + n) * NC + k];
  }

  float yacc[2][16];
  #pragma unroll
  for (int r = 0; r < 2; ++r)
    #pragma unroll
    for (int c = 0; c < 16; ++c) yacc[r][c] = 0.f;

  for (int m0 = 0; m0 < HW; m0 += 64) {
    // ---- S-compute: sacc[2][4] = X1[n0+2ti+r][:] . X2[:][m0+4tj+c], K=256 in 4 slices ----
    float sacc[2][4] = {{0.f, 0.f, 0.f, 0.f}, {0.f, 0.f, 0.f, 0.f}};
    for (int ks = 0; ks < 256; ks += 64) {
      __syncthreads();  // protect Bs (and, first iter, publish As / retire prior Ss reads)
      for (int i = tid; i < 64 * 64; i += 256) {
        const int kk = i >> 6, m = i & 63;
        Bs[kk][m] = xb[(size_t)(ks + kk) * HW + m0 + m];
      }
      __syncthreads();
      #pragma unroll 4
      for (int kk = 0; kk < 64; ++kk) {
        const float2 av = *(const float2*)&As[ks + kk][2 * ti];
        const float4 bv = *(const float4*)&Bs[kk][4 * tj];
        sacc[0][0] = fmaf(av.x, bv.x, sacc[0][0]);
        sacc[0][1] = fmaf(av.x, bv.y, sacc[0][1]);
        sacc[0][2] = fmaf(av.x, bv.z, sacc[0][2]);
        sacc[0][3] = fmaf(av.x, bv.w, sacc[0][3]);
        sacc[1][0] = fmaf(av.y, bv.x, sacc[1][0]);
        sacc[1][1] = fmaf(av.y, bv.y, sacc[1][1]);
        sacc[1][2] = fmaf(av.y, bv.z, sacc[1][2]);
        sacc[1][3] = fmaf(av.y, bv.w, sacc[1][3]);
      }
    }
    __syncthreads();  // all Ss readers of previous chunk are done
    #pragma unroll
    for (int r = 0; r < 2; ++r) {
      float4 sv;
      float p;
      p = fmaxf(sacc[r][0] * inv2, 0.f); sv.x = p * p;
      p = fmaxf(sacc[r][1] * inv2, 0.f); sv.y = p * p;
      p = fmaxf(sacc[r][2] * inv2, 0.f); sv.z = p * p;
      p = fmaxf(sacc[r][3] * inv2, 0.f); sv.w = p * p;
      *(float4*)&Ss[2 * ti + r][4 * tj] = sv;
    }
    __syncthreads();
    // ---- Y-accum: yacc[r][c] += Ss[2ti+r][mm] * TR[m0+mm][16tj+c]  (TR = flat-reindexed trbuf) ----
    for (int mm = 0; mm < 64; ++mm) {
      const float a0 = Ss[2 * ti + 0][mm];
      const float a1 = Ss[2 * ti + 1][mm];
      const float* trow = tb + (size_t)(m0 + mm) * NC + 16 * tj;  // flat index m*256+k
      float t[16];
      #pragma unroll
      for (int g = 0; g < 4; ++g) *(float4*)&t[4 * g] = *(const float4*)(trow + 4 * g);
      #pragma unroll
      for (int c = 0; c < 16; ++c) yacc[0][c] = fmaf(a0, t[c], yacc[0][c]);
      #pragma unroll
      for (int c = 0; c < 16; ++c) yacc[1][c] = fmaf(a1, t[c], yacc[1][c]);
    }
  }

  // ---- Epilogue: out flat = y flat: ob[(n0+n)*256 + k] ----
  #pragma unroll
  for (int r = 0; r < 2; ++r) {
    float* orow = ob + (size_t)(n0 + 2 * ti + r) * NC + 16 * tj;
    *(float4*)(orow + 0)  = make_float4(yacc[r][0],  yacc[r][1],  yacc[r][2],  yacc[r][3]);
    *(float4*)(orow + 4)  = make_float4(yacc[r][4],  yacc[r][5],  yacc[r][6],  yacc[r][7]);
    *(float4*)(orow + 8)  = make_float4(yacc[r][8],  yacc[r][9],  yacc[r][10], yacc[r][11]);
    *(float4*)(orow + 12) = make_float4(yacc[r][12], yacc[r][13], yacc[r][14], yacc[r][15]);
  }
}

extern "C" void kernel_launch(void* const* d_in, const int* in_sizes, int n_in,
                              void* d_out, int out_size, void* d_ws, size_t ws_size,
                              hipStream_t stream) {
  const float* x    = (const float*)d_in[0];
  const float* W    = (const float*)d_in[1];
  const float* bias = (const float*)d_in[2];
  float* out = (float*)d_out;

  // ws layout: [double partials 512][float inv_xn2 16][trbuf NB*CHW floats]
  double* partials = (double*)d_ws;                        // 4096 B
  float* inv_xn2   = (float*)((char*)d_ws + 4096);         // 64 B
  float* trbuf     = (float*)((char*)d_ws + 4096 + 64);    // 37,748,736 B

  sumsq_kernel<<<dim3(32, 16), 256, 0, stream>>>(x, partials);
  finish_kernel<<<16, 64, 0, stream>>>(partials, inv_xn2);
  conv_kernel<<<dim3(9, 16, 16), 256, 0, stream>>>(x, W, bias, trbuf);
  fused_kernel<<<dim3(72, 16), 256, 0, stream>>>(x, trbuf, inv_xn2, out);
}

// Round 2
// 627.040 us; speedup vs baseline: 5.4589x; 5.4589x over previous
//
#include <hip/hip_runtime.h>

#define NB 16
#define NC 256
#define HW 2304
#define CHW 589824  // NC*HW

typedef __attribute__((ext_vector_type(8))) short bf16x8;
typedef __attribute__((ext_vector_type(16))) float f32x16;

__device__ inline unsigned short f2bf(float f) {
  unsigned u = __builtin_bit_cast(unsigned, f);
  u += 0x7fffu + ((u >> 16) & 1u);  // RNE (inputs finite, no NaN handling)
  return (unsigned short)(u >> 16);
}

// ---------------- A1: per-batch partial sum of squares (fp64) ----------------
__global__ __launch_bounds__(256) void sumsq_kernel(const float* __restrict__ x,
                                                    double* __restrict__ partials) {
  const int j = blockIdx.x, b = blockIdx.y;
  const float* xb = x + (size_t)b * CHW;
  const int base = j * (CHW / 32);
  double acc = 0.0;
  for (int i = threadIdx.x; i < CHW / 32; i += 256) {
    float v = xb[base + i];
    acc += (double)v * (double)v;
  }
  __shared__ double red[256];
  red[threadIdx.x] = acc;
  __syncthreads();
  for (int s = 128; s > 0; s >>= 1) {
    if (threadIdx.x < s) red[threadIdx.x] += red[threadIdx.x + s];
    __syncthreads();
  }
  if (threadIdx.x == 0) partials[b * 32 + j] = red[0];
}

// ---------------- A2: finish reduction, write 1/xn^2 ----------------
__global__ __launch_bounds__(64) void finish_kernel(const double* __restrict__ partials,
                                                    float* __restrict__ inv_xn2) {
  const int b = blockIdx.x, t = threadIdx.x;
  double v = (t < 32) ? partials[b * 32 + t] : 0.0;
  #pragma unroll
  for (int off = 32; off > 0; off >>= 1) v += __shfl_down(v, off, 64);
  if (t == 0) inv_xn2[b] = (float)(1.0 / v);
}

// ---------------- B: 1x1 conv, bf16 output in trflat order ----------------
__global__ __launch_bounds__(256) void conv_kernel(const float* __restrict__ x,
                                                   const float* __restrict__ W,
                                                   const float* __restrict__ bias,
                                                   unsigned short* __restrict__ trbuf) {
  const int mt = blockIdx.x, c0 = blockIdx.y * 16, b = blockIdx.z;
  const int m = mt * 256 + threadIdx.x;
  const float* xb = x + (size_t)b * CHW;
  float acc[16];
  #pragma unroll
  for (int i = 0; i < 16; ++i) acc[i] = bias[c0 + i];
  #pragma unroll 4
  for (int k = 0; k < 256; ++k) {
    const float xv = xb[(size_t)k * HW + m];
    #pragma unroll
    for (int i = 0; i < 16; ++i)
      acc[i] = fmaf(W[(size_t)(c0 + i) * 256 + k], xv, acc[i]);  // W wave-uniform -> s_load
  }
  unsigned short* tb = trbuf + (size_t)b * CHW;
  #pragma unroll
  for (int i = 0; i < 16; ++i) tb[(size_t)(c0 + i) * HW + m] = f2bf(acc[i]);
}

// ---------------- P4: x -> x1bf (flat bf16) + xt (transposed bf16) ----------------
// xt[m*256+k] = v[k*2304+m]
__global__ __launch_bounds__(256) void xprep_kernel(const float* __restrict__ x,
                                                    unsigned short* __restrict__ x1bf,
                                                    unsigned short* __restrict__ xt) {
  const int m0 = blockIdx.x * 64, k0 = blockIdx.y * 64, b = blockIdx.z;
  const float* xb = x + (size_t)b * CHW;
  unsigned short* x1b = x1bf + (size_t)b * CHW;
  unsigned short* xtb = xt + (size_t)b * CHW;
  __shared__ float tile[64][65];
  const int q = threadIdx.x >> 6, mm = threadIdx.x & 63;
  #pragma unroll
  for (int rr = 0; rr < 16; ++rr) {
    const int kk = q * 16 + rr;
    float v = xb[(size_t)(k0 + kk) * HW + m0 + mm];
    tile[mm][kk] = v;
    x1b[(size_t)(k0 + kk) * HW + m0 + mm] = f2bf(v);
  }
  __syncthreads();
  const int kk2 = threadIdx.x & 63;
  #pragma unroll
  for (int rr = 0; rr < 16; ++rr) {
    const int mm2 = q * 16 + rr;
    xtb[(size_t)(m0 + mm2) * NC + k0 + kk2] = f2bf(tile[mm2][kk2]);
  }
}

// ---------------- P5: trflat(bf16) -> trT (256 x 2304, m contiguous) ----------------
// trT[k'*2304+m] = trflat[m*256+k']
__global__ __launch_bounds__(256) void trT_kernel(const unsigned short* __restrict__ trbuf,
                                                  unsigned short* __restrict__ trT) {
  const int m0 = blockIdx.x * 64, k0 = blockIdx.y * 64, b = blockIdx.z;
  const unsigned short* tb = trbuf + (size_t)b * CHW;
  unsigned short* tt = trT + (size_t)b * CHW;
  __shared__ unsigned short tile[64][66];
  const int q = threadIdx.x >> 6, kk = threadIdx.x & 63;
  #pragma unroll
  for (int rr = 0; rr < 16; ++rr) {
    const int mm = q * 16 + rr;
    tile[mm][kk] = tb[(size_t)(m0 + mm) * NC + k0 + kk];
  }
  __syncthreads();
  const int mm2 = threadIdx.x & 63;
  #pragma unroll
  for (int rr = 0; rr < 16; ++rr) {
    const int kk2 = q * 16 + rr;
    tt[(size_t)(k0 + kk2) * HW + m0 + mm2] = tile[mm2][kk2];
  }
}

// ---------------- F: fused flash-style MFMA kernel ----------------
// Per block: 64 rows (n), loop m in chunks of 64. S = X1*X2 (K=256), P = relu(S*inv2)^2,
// Y += P*TRT. mfma_f32_32x32x16_bf16; wave w: S-tile (r=w>>1, c=w&1); Y cols 128*(w&1)+...
__global__ __launch_bounds__(256, 2) void fused_kernel(const unsigned short* __restrict__ x1bf,
                                                       const unsigned short* __restrict__ xt,
                                                       const unsigned short* __restrict__ trT,
                                                       const float* __restrict__ inv_xn2,
                                                       float* __restrict__ out) {
  const int nt = blockIdx.x, b = blockIdx.y;
  const int n0 = nt * 64;
  const unsigned short* x1b = x1bf + (size_t)b * CHW;
  const unsigned short* xtb = xt + (size_t)b * CHW;
  const unsigned short* ttb = trT + (size_t)b * CHW;
  float* ob = (float*)out + (size_t)b * CHW;
  const float inv2 = inv_xn2[b];

  const int tid = threadIdx.x;
  const int w = tid >> 6, lane = tid & 63;
  const int lane31 = lane & 31, half = lane >> 5;
  const int r = w >> 1, c = w & 1;

  __shared__ unsigned short Pl[64][72];  // pitch 144B: conflict-free writes, 16B-aligned frag reads

  // X1 A-frags, register-resident: frag f = k[16f..16f+16); lane holds k = 16f+8*half+j
  bf16x8 af[16];
  {
    const unsigned short* ap = x1b + (size_t)(n0 + 32 * r + lane31) * NC + 8 * half;
    #pragma unroll
    for (int f = 0; f < 16; ++f) af[f] = *(const bf16x8*)(ap + 16 * f);
  }

  f32x16 yacc[4];
  #pragma unroll
  for (int cb = 0; cb < 4; ++cb)
    #pragma unroll
    for (int i = 0; i < 16; ++i) yacc[cb][i] = 0.f;

  for (int ch = 0; ch < 36; ++ch) {
    const int m0 = ch * 64;
    // ---- S phase: sacc = X1[32r..][:] * X2[:][m0+32c..]  (B-frags direct from xt) ----
    f32x16 sacc;
    #pragma unroll
    for (int i = 0; i < 16; ++i) sacc[i] = 0.f;
    const unsigned short* bp = xtb + (size_t)(m0 + 32 * c + lane31) * NC + 8 * half;
    #pragma unroll
    for (int f = 0; f < 16; ++f) {
      bf16x8 bfv = *(const bf16x8*)(bp + 16 * f);
      sacc = __builtin_amdgcn_mfma_f32_32x32x16_bf16(af[f], bfv, sacc, 0, 0, 0);
    }
    // ---- P = relu(sacc*inv2)^2 -> bf16 -> LDS (row-major, m contiguous) ----
    __syncthreads();  // previous chunk's Pl readers done
    #pragma unroll
    for (int reg = 0; reg < 16; ++reg) {
      const int rowp = (reg & 3) + 8 * (reg >> 2) + 4 * half;  // C/D row mapping
      float v = sacc[reg] * inv2;
      v = fmaxf(v, 0.f);
      v *= v;
      Pl[32 * r + rowp][32 * c + lane31] = f2bf(v);
    }
    __syncthreads();
    // ---- Y phase: yacc += P[32r..][0..64) * TRT-chunk ----
    bf16x8 pf[4];
    #pragma unroll
    for (int kf = 0; kf < 4; ++kf)
      pf[kf] = *(const bf16x8*)&Pl[32 * r + lane31][16 * kf + 8 * half];
    #pragma unroll
    for (int cb = 0; cb < 4; ++cb) {
      const unsigned short* tp = ttb + (size_t)(32 * (4 * c + cb) + lane31) * HW + m0 + 8 * half;
      #pragma unroll
      for (int kf = 0; kf < 4; ++kf) {
        bf16x8 bt = *(const bf16x8*)(tp + 16 * kf);
        yacc[cb] = __builtin_amdgcn_mfma_f32_32x32x16_bf16(pf[kf], bt, yacc[cb], 0, 0, 0);
      }
    }
  }

  // ---- Epilogue: out flat = y[n][k'] at ob[n*256+k'] ----
  #pragma unroll
  for (int cb = 0; cb < 4; ++cb) {
    const int k2 = 32 * (4 * c + cb) + lane31;
    #pragma unroll
    for (int reg = 0; reg < 16; ++reg) {
      const int rowp = (reg & 3) + 8 * (reg >> 2) + 4 * half;
      ob[(size_t)(n0 + 32 * r + rowp) * NC + k2] = yacc[cb][reg];
    }
  }
}

extern "C" void kernel_launch(void* const* d_in, const int* in_sizes, int n_in,
                              void* d_out, int out_size, void* d_ws, size_t ws_size,
                              hipStream_t stream) {
  const float* x    = (const float*)d_in[0];
  const float* W    = (const float*)d_in[1];
  const float* bias = (const float*)d_in[2];
  float* out = (float*)d_out;

  // ws: [partials 4KB][inv_xn2 4KB][trbuf bf16 18.87MB][x1bf 18.87MB][xt 18.87MB][trT 18.87MB]
  const size_t SZ = (size_t)NB * CHW * sizeof(unsigned short);  // 18,874,368
  double* partials        = (double*)d_ws;
  float* inv_xn2          = (float*)((char*)d_ws + 4096);
  unsigned short* trbuf   = (unsigned short*)((char*)d_ws + 8192);
  unsigned short* x1bf    = (unsigned short*)((char*)d_ws + 8192 + SZ);
  unsigned short* xt      = (unsigned short*)((char*)d_ws + 8192 + 2 * SZ);
  unsigned short* trT     = (unsigned short*)((char*)d_ws + 8192 + 3 * SZ);

  sumsq_kernel<<<dim3(32, 16), 256, 0, stream>>>(x, partials);
  finish_kernel<<<16, 64, 0, stream>>>(partials, inv_xn2);
  conv_kernel<<<dim3(9, 16, 16), 256, 0, stream>>>(x, W, bias, trbuf);
  xprep_kernel<<<dim3(36, 4, 16), 256, 0, stream>>>(x, x1bf, xt);
  trT_kernel<<<dim3(36, 4, 16), 256, 0, stream>>>(trbuf, trT);
  fused_kernel<<<dim3(36, 16), 256, 0, stream>>>(x1bf, xt, trT, inv_xn2, out);
}

// Round 3
// 369.949 us; speedup vs baseline: 9.2526x; 1.6949x over previous
//
#include <hip/hip_runtime.h>

#define NB 16
#define NC 256
#define HW 2304
#define CHW 589824  // NC*HW

typedef __attribute__((ext_vector_type(8))) short bf16x8;
typedef __attribute__((ext_vector_type(16))) float f32x16;

union BF8 { bf16x8 v; unsigned short u[8]; };

__device__ inline unsigned short f2bf(float f) {
  unsigned u = __builtin_bit_cast(unsigned, f);
  u += 0x7fffu + ((u >> 16) & 1u);  // RNE (inputs finite)
  return (unsigned short)(u >> 16);
}

// ---------------- x1pack: bf16 A-frags of X1 (flat view) + per-block sumsq ----------------
// x1p[b][nb][f][l][j] = v[(32nb + (l&31))*256 + 16f + 8*(l>>5) + j]
__global__ __launch_bounds__(256) void x1pack_kernel(const float* __restrict__ x,
                                                     unsigned short* __restrict__ x1p,
                                                     double* __restrict__ partials) {
  const int nb = blockIdx.x, b = blockIdx.y;
  const float* src = x + (size_t)b * CHW + nb * 8192;
  __shared__ float tile[32 * 257];  // pad 256->257: frag reads conflict-free
  __shared__ double red[256];
  const int tid = threadIdx.x;
  double ss = 0.0;
  for (int i = tid; i < 8192; i += 256) {
    float v = src[i];
    tile[(i >> 8) * 257 + (i & 255)] = v;
    ss += (double)v * (double)v;
  }
  red[tid] = ss;
  __syncthreads();
  for (int s = 128; s > 0; s >>= 1) {
    if (tid < s) red[tid] += red[tid + s];
    __syncthreads();
  }
  if (tid == 0) partials[b * 72 + nb] = red[0];
  const int w = tid >> 6, l = tid & 63, l31 = l & 31, h = l >> 5;
  unsigned short* dst = x1p + (size_t)b * CHW + (size_t)nb * 8192;
  #pragma unroll
  for (int ff = 0; ff < 4; ++ff) {
    const int f = 4 * w + ff;
    BF8 o;
    #pragma unroll
    for (int j = 0; j < 8; ++j)
      o.u[j] = f2bf(tile[l31 * 257 + 16 * f + 8 * h + j]);
    *(bf16x8*)(dst + (((size_t)f) * 64 + l) * 8) = o.v;
  }
}

// ---------------- finish: reduce 72 partials/batch -> 1/xn^2 ----------------
__global__ __launch_bounds__(64) void finish_kernel(const double* __restrict__ partials,
                                                    float* __restrict__ inv_xn2) {
  const int b = blockIdx.x, t = threadIdx.x;
  double v = partials[b * 72 + t];
  if (t < 8) v += partials[b * 72 + 64 + t];
  #pragma unroll
  for (int off = 32; off > 0; off >>= 1) v += __shfl_down(v, off, 64);
  if (t == 0) inv_xn2[b] = (float)(1.0 / v);
}

// ---------------- xtpack: bf16 B-frags of X2 (transposed view) ----------------
// xtp[b][mb][f][l][j] = x[b][k = 16f+8*(l>>5)+j][m = 32mb + (l&31)]
__global__ __launch_bounds__(256) void xtpack_kernel(const float* __restrict__ x,
                                                     unsigned short* __restrict__ xtp) {
  const int mt = blockIdx.x, kt = blockIdx.y, b = blockIdx.z;
  const int m0 = mt * 64, k0 = kt * 64;
  const float* xb = x + (size_t)b * CHW;
  __shared__ float tile[64][65];
  const int tid = threadIdx.x, q = tid >> 6, mm = tid & 63;
  #pragma unroll
  for (int rr = 0; rr < 16; ++rr) {
    const int kk = q * 16 + rr;
    tile[kk][mm] = xb[(size_t)(k0 + kk) * HW + m0 + mm];
  }
  __syncthreads();
  const int w = tid >> 6, l = tid & 63, l31 = l & 31, h = l >> 5;
  unsigned short* dst = xtp + (size_t)b * CHW;
  #pragma unroll
  for (int pp = 0; pp < 2; ++pp) {
    const int p = 2 * w + pp;  // 0..7
    const int mbl = p >> 2, fl = p & 3;
    BF8 o;
    #pragma unroll
    for (int j = 0; j < 8; ++j)
      o.u[j] = f2bf(tile[16 * fl + 8 * h + j][32 * mbl + l31]);
    const int mb = 2 * mt + mbl, f = 4 * kt + fl;
    *(bf16x8*)(dst + (((size_t)mb * 16 + f) * 64 + l) * 8) = o.v;
  }
}

// ---------------- conv (MFMA): trflat[c'][m] = sum_k W[c'][k]*x[b][k][m] + bias[c'] ----------------
__global__ __launch_bounds__(256, 2) void conv_kernel(const float* __restrict__ W,
                                                      const float* __restrict__ bias,
                                                      const unsigned short* __restrict__ xtp,
                                                      unsigned short* __restrict__ trflat) {
  const int ch = blockIdx.x, b = blockIdx.y;
  const int m0 = ch * 64;
  const int tid = threadIdx.x, w = tid >> 6, l = tid & 63, l31 = l & 31, h = l >> 5;
  const unsigned short* xb = xtp + (size_t)b * CHW;
  unsigned short* tb = trflat + (size_t)b * CHW;
  // A-frags from fp32 W, converted in-register (W is L2-resident, loaded once/block)
  bf16x8 af[2][16];
  #pragma unroll
  for (int rb = 0; rb < 2; ++rb) {
    const int row = 32 * (w + 4 * rb) + l31;
    const float* wp = W + (size_t)row * 256 + 8 * h;
    #pragma unroll
    for (int f = 0; f < 16; ++f) {
      float4 u0 = *(const float4*)(wp + 16 * f);
      float4 u1 = *(const float4*)(wp + 16 * f + 4);
      BF8 o;
      o.u[0] = f2bf(u0.x); o.u[1] = f2bf(u0.y); o.u[2] = f2bf(u0.z); o.u[3] = f2bf(u0.w);
      o.u[4] = f2bf(u1.x); o.u[5] = f2bf(u1.y); o.u[6] = f2bf(u1.z); o.u[7] = f2bf(u1.w);
      af[rb][f] = o.v;
    }
  }
  f32x16 yacc[2][2];
  #pragma unroll
  for (int rb = 0; rb < 2; ++rb)
    #pragma unroll
    for (int cb = 0; cb < 2; ++cb)
      #pragma unroll
      for (int i = 0; i < 16; ++i) yacc[rb][cb][i] = 0.f;
  #pragma unroll 4
  for (int f = 0; f < 16; ++f) {
    #pragma unroll
    for (int cb = 0; cb < 2; ++cb) {
      const int mb = 2 * ch + cb;
      bf16x8 bv = *(const bf16x8*)(xb + (((size_t)mb * 16 + f) * 64 + l) * 8);
      yacc[0][cb] = __builtin_amdgcn_mfma_f32_32x32x16_bf16(af[0][f], bv, yacc[0][cb], 0, 0, 0);
      yacc[1][cb] = __builtin_amdgcn_mfma_f32_32x32x16_bf16(af[1][f], bv, yacc[1][cb], 0, 0, 0);
    }
  }
  #pragma unroll
  for (int rb = 0; rb < 2; ++rb)
    #pragma unroll
    for (int reg = 0; reg < 16; ++reg) {
      const int row = 32 * (w + 4 * rb) + (reg & 3) + 8 * (reg >> 2) + 4 * h;
      const float bv = bias[row];
      #pragma unroll
      for (int cb = 0; cb < 2; ++cb)
        tb[(size_t)row * HW + m0 + 32 * cb + l31] = f2bf(yacc[rb][cb][reg] + bv);
    }
}

// ---------------- trpack: trflat -> B-frags of TR for Y GEMM ----------------
// trp[b][mb][cb8][kf][l][j] = trflat[(64mb + 16kf + 8*(l>>5) + j)*256 + 32cb8 + (l&31)]
__global__ __launch_bounds__(256) void trpack_kernel(const unsigned short* __restrict__ trflat,
                                                     unsigned short* __restrict__ trp) {
  const int mb = blockIdx.x, b = blockIdx.y;
  const unsigned* src = (const unsigned*)(trflat + (size_t)b * CHW + (size_t)mb * 16384);
  __shared__ unsigned short tile[64 * 258];  // pitch 258 shorts spreads banks
  const int tid = threadIdx.x;
  for (int i = tid; i < 8192; i += 256) {
    const int row = i >> 7, col2 = i & 127;
    ((unsigned*)&tile[row * 258])[col2] = src[i];
  }
  __syncthreads();
  const int kf = tid >> 6, l = tid & 63, l31 = l & 31, h = l >> 5;
  unsigned short* dst = trp + (size_t)b * CHW + (size_t)mb * 16384;
  #pragma unroll
  for (int cb8 = 0; cb8 < 8; ++cb8) {
    BF8 o;
    #pragma unroll
    for (int j = 0; j < 8; ++j)
      o.u[j] = tile[(16 * kf + 8 * h + j) * 258 + 32 * cb8 + l31];
    *(bf16x8*)(dst + (((size_t)cb8 * 4 + kf) * 64 + l) * 8) = o.v;
  }
}

// ---------------- fused: y = relu(X1*X2/xn^2)^2 * TR, all-coalesced frag loads ----------------
__global__ __launch_bounds__(256, 2) void fused_kernel(const unsigned short* __restrict__ x1p,
                                                       const unsigned short* __restrict__ xtp,
                                                       const unsigned short* __restrict__ trp,
                                                       const float* __restrict__ inv_xn2,
                                                       float* __restrict__ out) {
  const int bid = blockIdx.x;
  const int j = bid >> 3, xcd = bid & 7;  // assume round-robin bid%8 -> XCD
  const int hi = (j >= 36) ? 1 : 0;
  const int b = xcd + 8 * hi;        // one batch per XCD at a time -> L2-local
  const int nt = j - 36 * hi;
  const int n0 = nt * 64;
  const unsigned short* x1b = x1p + (size_t)b * CHW;
  const unsigned short* xtb = xtp + (size_t)b * CHW;
  const unsigned short* ttb = trp + (size_t)b * CHW;
  float* ob = out + (size_t)b * CHW;
  const float inv2 = inv_xn2[b];

  const int tid = threadIdx.x;
  const int w = tid >> 6, lane = tid & 63;
  const int l31 = lane & 31, h = lane >> 5;
  const int r = w >> 1, c = w & 1;

  __shared__ unsigned short Pl[2][64][72];  // double-buffered P, pitch 144 B

  // A-frags (register-resident across all chunks)
  bf16x8 af[16];
  {
    const unsigned short* ap = x1b + (((size_t)(2 * nt + r)) * 16) * 512 + lane * 8;
    #pragma unroll
    for (int f = 0; f < 16; ++f) af[f] = *(const bf16x8*)(ap + f * 512);
  }

  f32x16 yacc[4];
  #pragma unroll
  for (int cb = 0; cb < 4; ++cb)
    #pragma unroll
    for (int i = 0; i < 16; ++i) yacc[cb][i] = 0.f;

  for (int ch = 0; ch < 36; ++ch) {
    const int pb = ch & 1;
    // ---- S phase: 16 coalesced B-frag loads + 16 MFMAs ----
    f32x16 sacc;
    #pragma unroll
    for (int i = 0; i < 16; ++i) sacc[i] = 0.f;
    const unsigned short* bp = xtb + ((size_t)(2 * ch + c) * 16) * 512 + lane * 8;
    #pragma unroll
    for (int f = 0; f < 16; ++f) {
      bf16x8 bfv = *(const bf16x8*)(bp + f * 512);
      sacc = __builtin_amdgcn_mfma_f32_32x32x16_bf16(af[f], bfv, sacc, 0, 0, 0);
    }
    // ---- prefetch Y B-frags (complete by the barrier's vmcnt drain) ----
    bf16x8 bt[16];
    const unsigned short* tp = ttb + (size_t)ch * 16384 + lane * 8;
    #pragma unroll
    for (int cb = 0; cb < 4; ++cb)
      #pragma unroll
      for (int kf = 0; kf < 4; ++kf)
        bt[cb * 4 + kf] = *(const bf16x8*)(tp + (((size_t)(4 * c + cb) * 4 + kf)) * 512);
    // ---- P = relu(s*inv2)^2 -> bf16 -> LDS ----
    #pragma unroll
    for (int reg = 0; reg < 16; ++reg) {
      const int rowp = (reg & 3) + 8 * (reg >> 2) + 4 * h;
      float v = sacc[reg] * inv2;
      v = fmaxf(v, 0.f);
      v *= v;
      Pl[pb][32 * r + rowp][32 * c + l31] = f2bf(v);
    }
    __syncthreads();  // single barrier per chunk (double-buffered P)
    bf16x8 pf[4];
    #pragma unroll
    for (int kf = 0; kf < 4; ++kf)
      pf[kf] = *(const bf16x8*)&Pl[pb][32 * r + l31][16 * kf + 8 * h];
    // ---- Y phase: 16 MFMAs on prefetched frags ----
    #pragma unroll
    for (int cb = 0; cb < 4; ++cb)
      #pragma unroll
      for (int kf = 0; kf < 4; ++kf)
        yacc[cb] = __builtin_amdgcn_mfma_f32_32x32x16_bf16(pf[kf], bt[cb * 4 + kf], yacc[cb], 0, 0, 0);
  }

  // ---- epilogue: out flat at ob[n*256 + k'] ----
  #pragma unroll
  for (int cb = 0; cb < 4; ++cb) {
    const int k2 = 32 * (4 * c + cb) + l31;
    #pragma unroll
    for (int reg = 0; reg < 16; ++reg) {
      const int rowp = (reg & 3) + 8 * (reg >> 2) + 4 * h;
      ob[(size_t)(n0 + 32 * r + rowp) * NC + k2] = yacc[cb][reg];
    }
  }
}

extern "C" void kernel_launch(void* const* d_in, const int* in_sizes, int n_in,
                              void* d_out, int out_size, void* d_ws, size_t ws_size,
                              hipStream_t stream) {
  const float* x    = (const float*)d_in[0];
  const float* W    = (const float*)d_in[1];
  const float* bias = (const float*)d_in[2];
  float* out = (float*)d_out;

  const size_t SZ = (size_t)NB * CHW * sizeof(unsigned short);  // 18,874,368 B
  double* partials      = (double*)d_ws;                             // 9216 B used
  float* inv_xn2        = (float*)((char*)d_ws + 16384);
  unsigned short* x1p   = (unsigned short*)((char*)d_ws + 32768);
  unsigned short* xtp   = (unsigned short*)((char*)d_ws + 32768 + SZ);
  unsigned short* trflat= (unsigned short*)((char*)d_ws + 32768 + 2 * SZ);
  unsigned short* trp   = (unsigned short*)((char*)d_ws + 32768 + 3 * SZ);

  x1pack_kernel<<<dim3(72, 16), 256, 0, stream>>>(x, x1p, partials);
  finish_kernel<<<16, 64, 0, stream>>>(partials, inv_xn2);
  xtpack_kernel<<<dim3(36, 4, 16), 256, 0, stream>>>(x, xtp);
  conv_kernel<<<dim3(36, 16), 256, 0, stream>>>(W, bias, xtp, trflat);
  trpack_kernel<<<dim3(36, 16), 256, 0, stream>>>(trflat, trp);
  fused_kernel<<<576, 256, 0, stream>>>(x1p, xtp, trp, inv_xn2, out);
}

// Round 4
// 302.832 us; speedup vs baseline: 11.3032x; 1.2216x over previous
//
#include <hip/hip_runtime.h>

#define NB 16
#define NC 256
#define HW 2304
#define CHW 589824  // NC*HW

typedef __attribute__((ext_vector_type(8))) short bf16x8;
typedef __attribute__((ext_vector_type(16))) float f32x16;

union BF8 { bf16x8 v; unsigned short u[8]; };

__device__ inline unsigned short f2bf(float f) {
  unsigned u = __builtin_bit_cast(unsigned, f);
  u += 0x7fffu + ((u >> 16) & 1u);  // RNE (inputs finite)
  return (unsigned short)(u >> 16);
}

// ---------------- x1pack: bf16 A-frags of X1 (flat view) + per-block sumsq ----------------
// x1p[b][nb][f][l][j] = v[(32nb + (l&31))*256 + 16f + 8*(l>>5) + j]
__global__ __launch_bounds__(256) void x1pack_kernel(const float* __restrict__ x,
                                                     unsigned short* __restrict__ x1p,
                                                     double* __restrict__ partials) {
  const int nb = blockIdx.x, b = blockIdx.y;
  const float4* src = (const float4*)(x + (size_t)b * CHW + nb * 8192);
  __shared__ float tile[32 * 260];  // pitch 260 (16B-aligned float4 stores)
  __shared__ double red[4];
  const int tid = threadIdx.x;
  double ss = 0.0;
  #pragma unroll
  for (int it = 0; it < 8; ++it) {
    const int i = tid + 256 * it;
    float4 v = src[i];
    const int fi = 4 * i, row = fi >> 8, col = fi & 255;
    *(float4*)&tile[row * 260 + col] = v;
    ss += (double)v.x * v.x + (double)v.y * v.y + (double)v.z * v.z + (double)v.w * v.w;
  }
  #pragma unroll
  for (int off = 32; off > 0; off >>= 1) ss += __shfl_down(ss, off, 64);
  const int w = tid >> 6, l = tid & 63;
  if (l == 0) red[w] = ss;
  __syncthreads();
  if (tid == 0) partials[b * 72 + nb] = red[0] + red[1] + red[2] + red[3];
  const int l31 = l & 31, h = l >> 5;
  unsigned short* dst = x1p + (size_t)b * CHW + (size_t)nb * 8192;
  #pragma unroll
  for (int ff = 0; ff < 4; ++ff) {
    const int f = 4 * w + ff;
    BF8 o;
    #pragma unroll
    for (int j = 0; j < 8; ++j)
      o.u[j] = f2bf(tile[l31 * 260 + 16 * f + 8 * h + j]);
    *(bf16x8*)(dst + (((size_t)f) * 64 + l) * 8) = o.v;
  }
}

// ---------------- finish: reduce 72 partials/batch -> 1/xn^2 ----------------
__global__ __launch_bounds__(64) void finish_kernel(const double* __restrict__ partials,
                                                    float* __restrict__ inv_xn2) {
  const int b = blockIdx.x, t = threadIdx.x;
  double v = partials[b * 72 + t];
  if (t < 8) v += partials[b * 72 + 64 + t];
  #pragma unroll
  for (int off = 32; off > 0; off >>= 1) v += __shfl_down(v, off, 64);
  if (t == 0) inv_xn2[b] = (float)(1.0 / v);
}

// ---------------- xtpack: bf16 B-frags of X2 (transposed view) ----------------
// xtp[b][mb][f][l][j] = x[b][k = 16f+8*(l>>5)+j][m = 32mb + (l&31)]
__global__ __launch_bounds__(256) void xtpack_kernel(const float* __restrict__ x,
                                                     unsigned short* __restrict__ xtp) {
  const int mt = blockIdx.x, kt = blockIdx.y, b = blockIdx.z;
  const int m0 = mt * 64, k0 = kt * 64;
  const float* xb = x + (size_t)b * CHW;
  __shared__ float tile[64 * 68];  // pitch 68 (16B-aligned)
  const int tid = threadIdx.x;
  #pragma unroll
  for (int it = 0; it < 4; ++it) {
    const int i = tid + 256 * it;
    const int row = i >> 4, c4 = (i & 15) * 4;
    float4 v = *(const float4*)(xb + (size_t)(k0 + row) * HW + m0 + c4);
    *(float4*)&tile[row * 68 + c4] = v;
  }
  __syncthreads();
  const int w = tid >> 6, l = tid & 63, l31 = l & 31, h = l >> 5;
  unsigned short* dst = xtp + (size_t)b * CHW;
  #pragma unroll
  for (int pp = 0; pp < 2; ++pp) {
    const int p = 2 * w + pp, mbl = p >> 2, fl = p & 3;
    BF8 o;
    #pragma unroll
    for (int j = 0; j < 8; ++j)
      o.u[j] = f2bf(tile[(16 * fl + 8 * h + j) * 68 + 32 * mbl + l31]);
    const int mb = 2 * mt + mbl, f = 4 * kt + fl;
    *(bf16x8*)(dst + (((size_t)mb * 16 + f) * 64 + l) * 8) = o.v;
  }
}

// ---------------- conv (MFMA): trflat[c'][m] = sum_k W[c'][k]*x[b][k][m] + bias[c'] ----------------
__global__ __launch_bounds__(256, 2) void conv_kernel(const float* __restrict__ W,
                                                      const float* __restrict__ bias,
                                                      const unsigned short* __restrict__ xtp,
                                                      unsigned short* __restrict__ trflat) {
  const int bid = blockIdx.x;
  const int xcd = bid & 7, j = bid >> 3;
  const int hi = (j >= 36) ? 1 : 0;
  const int b = xcd + 8 * hi;      // XCD-local batch
  const int ch = j - 36 * hi;
  const int m0 = ch * 64;
  const int tid = threadIdx.x, w = tid >> 6, l = tid & 63, l31 = l & 31, h = l >> 5;
  const unsigned short* xb = xtp + (size_t)b * CHW;
  unsigned short* tb = trflat + (size_t)b * CHW;
  bf16x8 af[2][16];
  #pragma unroll
  for (int rb = 0; rb < 2; ++rb) {
    const int row = 32 * (w + 4 * rb) + l31;
    const float* wp = W + (size_t)row * 256 + 8 * h;
    #pragma unroll
    for (int f = 0; f < 16; ++f) {
      float4 u0 = *(const float4*)(wp + 16 * f);
      float4 u1 = *(const float4*)(wp + 16 * f + 4);
      BF8 o;
      o.u[0] = f2bf(u0.x); o.u[1] = f2bf(u0.y); o.u[2] = f2bf(u0.z); o.u[3] = f2bf(u0.w);
      o.u[4] = f2bf(u1.x); o.u[5] = f2bf(u1.y); o.u[6] = f2bf(u1.z); o.u[7] = f2bf(u1.w);
      af[rb][f] = o.v;
    }
  }
  f32x16 yacc[2][2];
  #pragma unroll
  for (int rb = 0; rb < 2; ++rb)
    #pragma unroll
    for (int cb = 0; cb < 2; ++cb)
      #pragma unroll
      for (int i = 0; i < 16; ++i) yacc[rb][cb][i] = 0.f;
  #pragma unroll 4
  for (int f = 0; f < 16; ++f) {
    #pragma unroll
    for (int cb = 0; cb < 2; ++cb) {
      const int mb = 2 * ch + cb;
      bf16x8 bv = *(const bf16x8*)(xb + (((size_t)mb * 16 + f) * 64 + l) * 8);
      yacc[0][cb] = __builtin_amdgcn_mfma_f32_32x32x16_bf16(af[0][f], bv, yacc[0][cb], 0, 0, 0);
      yacc[1][cb] = __builtin_amdgcn_mfma_f32_32x32x16_bf16(af[1][f], bv, yacc[1][cb], 0, 0, 0);
    }
  }
  #pragma unroll
  for (int rb = 0; rb < 2; ++rb)
    #pragma unroll
    for (int reg = 0; reg < 16; ++reg) {
      const int row = 32 * (w + 4 * rb) + (reg & 3) + 8 * (reg >> 2) + 4 * h;
      const float bv = bias[row];
      #pragma unroll
      for (int cb = 0; cb < 2; ++cb)
        tb[(size_t)row * HW + m0 + 32 * cb + l31] = f2bf(yacc[rb][cb][reg] + bv);
    }
}

// ---------------- trpack: trflat -> B-frags of TR for Y GEMM (fine grid, 16B loads) ----------------
// trp[b][mb][cb8][kf][l][j] = trflat_flat[(64mb + 16kf + 8*(l>>5) + j)*256 + 32cb8 + (l&31)]
__global__ __launch_bounds__(256) void trpack_kernel(const unsigned short* __restrict__ trflat,
                                                     unsigned short* __restrict__ trp) {
  const int mb = blockIdx.x, half = blockIdx.y, b = blockIdx.z;
  const unsigned short* src = trflat + (size_t)b * CHW + (size_t)mb * 16384 + 128 * half;
  __shared__ unsigned short tile[64 * 136];
  const int tid = threadIdx.x;
  #pragma unroll
  for (int it = 0; it < 4; ++it) {
    const int i = tid + 256 * it;           // short8 index in [64][16]
    const int row = i >> 4, c8 = (i & 15) * 8;
    *(uint4*)&tile[row * 136 + c8] = *(const uint4*)(src + (size_t)row * 256 + c8);
  }
  __syncthreads();
  const int kf = tid >> 6, l = tid & 63, l31 = l & 31, h = l >> 5;
  unsigned short* dst = trp + (size_t)b * CHW + (size_t)mb * 16384;
  #pragma unroll
  for (int cl = 0; cl < 4; ++cl) {
    BF8 o;
    #pragma unroll
    for (int j = 0; j < 8; ++j)
      o.u[j] = tile[(16 * kf + 8 * h + j) * 136 + 32 * cl + l31];
    const int cb8 = 4 * half + cl;
    *(bf16x8*)(dst + (((size_t)cb8 * 4 + kf) * 64 + l) * 8) = o.v;
  }
}

// ---------------- fused: n32 tiles, 1152 blocks, A-frags in LDS, chunk=128 ----------------
__global__ __launch_bounds__(256, 3) void fused_kernel(const unsigned short* __restrict__ x1p,
                                                       const unsigned short* __restrict__ xtp,
                                                       const unsigned short* __restrict__ trp,
                                                       const float* __restrict__ inv_xn2,
                                                       float* __restrict__ out) {
  const int bid = blockIdx.x;
  const int xcd = bid & 7, j = bid >> 3;     // j in [0,144)
  const int hi = (j >= 72) ? 1 : 0;
  const int b = xcd + 8 * hi;                // one batch per XCD at a time
  const int nt = j - 72 * hi;                // [0,72) n-tile of 32 rows
  const unsigned short* x1b = x1p + (size_t)b * CHW + (size_t)nt * 8192;
  const unsigned short* xtb = xtp + (size_t)b * CHW;
  const unsigned short* ttb = trp + (size_t)b * CHW;
  float* ob = out + (size_t)b * CHW;
  const float inv2 = inv_xn2[b];

  const int tid = threadIdx.x;
  const int c = tid >> 6, lane = tid & 63;   // wave c = S-col / Y-col group
  const int l31 = lane & 31, h = lane >> 5;

  __shared__ unsigned short Af[8192];        // 16 A-frags x 512 shorts (16 KB)
  __shared__ unsigned short Pl[2][32][136];  // double-buffered P

  {  // stage A-frags (coalesced 16B) into LDS once
    const uint4* gsrc = (const uint4*)x1b;
    uint4* ldst = (uint4*)Af;
    #pragma unroll
    for (int it = 0; it < 4; ++it) ldst[tid + 256 * it] = gsrc[tid + 256 * it];
  }
  __syncthreads();

  f32x16 yacc[2];
  #pragma unroll
  for (int cb = 0; cb < 2; ++cb)
    #pragma unroll
    for (int i = 0; i < 16; ++i) yacc[cb][i] = 0.f;

  for (int ch = 0; ch < 18; ++ch) {
    const int pb = ch & 1;
    // ---- S phase: two 8-MFMA chains (halved dep latency), A from LDS ----
    const unsigned short* bp = xtb + ((size_t)(4 * ch + c) * 16) * 512 + lane * 8;
    bf16x8 b0[8], b1[8];
    #pragma unroll
    for (int f = 0; f < 8; ++f) b0[f] = *(const bf16x8*)(bp + f * 512);
    #pragma unroll
    for (int f = 0; f < 8; ++f) b1[f] = *(const bf16x8*)(bp + (f + 8) * 512);
    f32x16 s0, s1;
    #pragma unroll
    for (int i = 0; i < 16; ++i) { s0[i] = 0.f; s1[i] = 0.f; }
    #pragma unroll
    for (int f = 0; f < 8; ++f) {
      bf16x8 a0 = *(const bf16x8*)(Af + f * 512 + lane * 8);
      s0 = __builtin_amdgcn_mfma_f32_32x32x16_bf16(a0, b0[f], s0, 0, 0, 0);
    }
    #pragma unroll
    for (int f = 0; f < 8; ++f) {
      bf16x8 a1 = *(const bf16x8*)(Af + (f + 8) * 512 + lane * 8);
      s1 = __builtin_amdgcn_mfma_f32_32x32x16_bf16(a1, b1[f], s1, 0, 0, 0);
    }
    // ---- prefetch Y B-frags for cb=0 ----
    bf16x8 bt0[8];
    #pragma unroll
    for (int kk = 0; kk < 8; ++kk) {
      const size_t mb = 2 * ch + (kk >> 2);
      bt0[kk] = *(const bf16x8*)(ttb + mb * 16384 + ((size_t)((2 * c) * 4 + (kk & 3))) * 512 + lane * 8);
    }
    // ---- P = relu((s0+s1)*inv2)^2 -> bf16 -> LDS ----
    #pragma unroll
    for (int reg = 0; reg < 16; ++reg) {
      const int rowp = (reg & 3) + 8 * (reg >> 2) + 4 * h;
      float v = (s0[reg] + s1[reg]) * inv2;
      v = fmaxf(v, 0.f);
      v *= v;
      Pl[pb][rowp][32 * c + l31] = f2bf(v);
    }
    __syncthreads();  // single barrier per chunk (double-buffered P)
    // ---- P A-frags + cb=1 B-frags ----
    bf16x8 pf[8];
    #pragma unroll
    for (int kk = 0; kk < 8; ++kk)
      pf[kk] = *(const bf16x8*)&Pl[pb][l31][16 * kk + 8 * h];
    bf16x8 bt1[8];
    #pragma unroll
    for (int kk = 0; kk < 8; ++kk) {
      const size_t mb = 2 * ch + (kk >> 2);
      bt1[kk] = *(const bf16x8*)(ttb + mb * 16384 + ((size_t)((2 * c + 1) * 4 + (kk & 3))) * 512 + lane * 8);
    }
    // ---- Y phase: 16 MFMAs, two independent chains ----
    #pragma unroll
    for (int kk = 0; kk < 8; ++kk)
      yacc[0] = __builtin_amdgcn_mfma_f32_32x32x16_bf16(pf[kk], bt0[kk], yacc[0], 0, 0, 0);
    #pragma unroll
    for (int kk = 0; kk < 8; ++kk)
      yacc[1] = __builtin_amdgcn_mfma_f32_32x32x16_bf16(pf[kk], bt1[kk], yacc[1], 0, 0, 0);
  }

  // ---- epilogue: out flat at ob[n*256 + k'] ----
  #pragma unroll
  for (int cb = 0; cb < 2; ++cb) {
    const int col = 64 * c + 32 * cb + l31;
    #pragma unroll
    for (int reg = 0; reg < 16; ++reg) {
      const int rowp = (reg & 3) + 8 * (reg >> 2) + 4 * h;
      ob[(size_t)(32 * nt + rowp) * NC + col] = yacc[cb][reg];
    }
  }
}

extern "C" void kernel_launch(void* const* d_in, const int* in_sizes, int n_in,
                              void* d_out, int out_size, void* d_ws, size_t ws_size,
                              hipStream_t stream) {
  const float* x    = (const float*)d_in[0];
  const float* W    = (const float*)d_in[1];
  const float* bias = (const float*)d_in[2];
  float* out = (float*)d_out;

  const size_t SZ = (size_t)NB * CHW * sizeof(unsigned short);  // 18,874,368 B
  double* partials       = (double*)d_ws;
  float* inv_xn2         = (float*)((char*)d_ws + 16384);
  unsigned short* x1p    = (unsigned short*)((char*)d_ws + 32768);
  unsigned short* xtp    = (unsigned short*)((char*)d_ws + 32768 + SZ);
  unsigned short* trflat = (unsigned short*)((char*)d_ws + 32768 + 2 * SZ);
  unsigned short* trp    = (unsigned short*)((char*)d_ws + 32768 + 3 * SZ);

  x1pack_kernel<<<dim3(72, 16), 256, 0, stream>>>(x, x1p, partials);
  finish_kernel<<<16, 64, 0, stream>>>(partials, inv_xn2);
  xtpack_kernel<<<dim3(36, 4, 16), 256, 0, stream>>>(x, xtp);
  conv_kernel<<<576, 256, 0, stream>>>(W, bias, xtp, trflat);
  trpack_kernel<<<dim3(36, 2, 16), 256, 0, stream>>>(trflat, trp);
  fused_kernel<<<1152, 256, 0, stream>>>(x1p, xtp, trp, inv_xn2, out);
}